// Round 19
// baseline (7216.488 us; speedup 1.0000x reference)
//
#include <hip/hip_runtime.h>
#include <hip/hip_bf16.h>

#pragma clang fp contract(off)

#define NTH   1024      // 16 waves, 1 block per CU
#define PPT   16        // NTH*PPT == NPTS
#define NPTS  16384
#define BATCH 16
#define CFEAT 128
#define SMAX  4096
#define NWAVE (NTH / 64)
// Prune margin (r15-proven exact): skip iff lb*PRUNE_C >= waveMaxD.
#define PRUNE_C 0.999995f

__device__ __forceinline__ unsigned spread3(unsigned v) {
    v &= 0x3FFu;
    v = (v | (v << 16)) & 0x030000FFu;
    v = (v | (v << 8))  & 0x0300F00Fu;
    v = (v | (v << 4))  & 0x030C30C3u;
    v = (v | (v << 2))  & 0x09249249u;
    return v;
}
__device__ __forceinline__ unsigned qz10(float v) {
    int q = (int)((v + 6.0f) * (1023.0f / 12.0f));   // layout-only
    q = q < 0 ? 0 : (q > 1023 ? 1023 : q);
    return (unsigned)q;
}
__device__ __forceinline__ unsigned morton30(float x, float y, float z) {
    return (spread3(qz10(x)) << 2) | (spread3(qz10(y)) << 1) | spread3(qz10(z));
}

// ---------------------------------------------------------------------------
// FPS kernel, one block per batch.
// CORRECTNESS INVARIANTS (proven r0-r18; do not change):
//   * d  = fma(dz,dz, fma(dx,dx, dy*dy))   [XLA contraction form]
//   * md = fminf(D[k], d)
//   * argmax: max value, ties -> LOWEST ORIGINAL point index
//   * emission: idx[t] = last BEFORE the update pass
// r19 machinery (r18 + publish-path surgery; update loop untouched):
//   * persistent double-buffered per-wave slots {pack, x,y,z} replace the
//     atomicMax rotating cell (16 serialized same-address LDS atomics) AND
//     the uniform global coord fetch (~275cyc L2) on the critical path.
//   * updating wave: ballot candidates; owner = unique candidate, or (rare,
//     wave-uniform popcount>1, exact value ties only) shfl-min over mo.
//     Owner's rescan also grabs the coords of its lowest-k-at-max point.
//   * skipped wave: lane0 copies its slot across parity (D unchanged =>
//     pack+coords still valid). r17-proven race-free: iter-t scanners read
//     parity buf while iter-t+1 writers touch parity buf^1 only.
//   * post-barrier: 16-slot broadcast scan (conflict-free), coords from slot.
//   * rest r18-verbatim: counting sort, wave bbox prune, value-only update,
//     DPP wave max, LDS idx ring dumped after the loop.
// ---------------------------------------------------------------------------
template <bool FUSED>
__global__ __launch_bounds__(NTH) void fps_kernel(const float* __restrict__ xyz,
                                                  const float* __restrict__ x,
                                                  int* __restrict__ idx_out,
                                                  float* __restrict__ out,
                                                  int S) {
    const int b    = blockIdx.x;
    const int tid  = threadIdx.x;
    const int wid  = tid >> 6;
    const int lane = tid & 63;
    const float* __restrict__ xb = xyz + (size_t)b * 3 * NPTS;

    __shared__ unsigned s_ord[NPTS];            // 64 KB: sorted pos -> orig idx
    __shared__ unsigned s_hist[256];
    __shared__ unsigned long long s_wpk[2][NWAVE];
    __shared__ float    s_cx[2][NWAVE], s_cy[2][NWAVE], s_cz[2][NWAVE];
    __shared__ int      s_idx[SMAX];            // idx ring (always LDS)

    // ---- phase 0a: bucket histogram
    for (int i = tid; i < 256; i += NTH) s_hist[i] = 0;
    __syncthreads();
    for (int k = 0; k < PPT; ++k) {
        const int p = k * NTH + tid;
        const unsigned m = morton30(xb[p], xb[NPTS + p], xb[2 * NPTS + p]);
        atomicAdd(&s_hist[m >> 22], 1u);
    }
    __syncthreads();
    // ---- phase 0b: exclusive prefix (serial, one-time)
    if (tid == 0) {
        unsigned acc = 0;
        for (int i = 0; i < 256; ++i) { const unsigned c = s_hist[i]; s_hist[i] = acc; acc += c; }
    }
    __syncthreads();
    // ---- phase 0c: scatter orig indices to sorted order
    for (int k = 0; k < PPT; ++k) {
        const int p = k * NTH + tid;
        const unsigned m = morton30(xb[p], xb[NPTS + p], xb[2 * NPTS + p]);
        const unsigned pos = atomicAdd(&s_hist[m >> 22], 1u);
        s_ord[pos] = (unsigned)p;
    }
    __syncthreads();

    // ---- phase 0d: wave-chunk gather + wave bbox (r17-proven layout)
    float X[PPT], Y[PPT], Z[PPT], D[PPT];
    unsigned VI[PPT / 2];
    float bxl =  INFINITY, byl =  INFINITY, bzl =  INFINITY;
    float bxh = -INFINITY, byh = -INFINITY, bzh = -INFINITY;
#pragma unroll
    for (int k = 0; k < PPT; ++k) {
        const unsigned gi = s_ord[wid * (64 * PPT) + k * 64 + lane];
        const float xx = xb[gi], yy = xb[NPTS + gi], zz = xb[2 * NPTS + gi];
        X[k] = xx; Y[k] = yy; Z[k] = zz; D[k] = INFINITY;
        if ((k & 1) == 0) VI[k >> 1] = gi;
        else              VI[k >> 1] |= (gi << 16);
        bxl = fminf(bxl, xx); bxh = fmaxf(bxh, xx);
        byl = fminf(byl, yy); byh = fmaxf(byh, yy);
        bzl = fminf(bzl, zz); bzh = fmaxf(bzh, zz);
    }
#pragma unroll
    for (int off = 32; off >= 1; off >>= 1) {
        bxl = fminf(bxl, __shfl_xor(bxl, off)); bxh = fmaxf(bxh, __shfl_xor(bxh, off));
        byl = fminf(byl, __shfl_xor(byl, off)); byh = fmaxf(byh, __shfl_xor(byh, off));
        bzl = fminf(bzl, __shfl_xor(bzl, off)); bzh = fmaxf(bzh, __shfl_xor(bzh, off));
    }

    int   last  = 0;
    float px = xb[0], py = xb[NPTS], pz = xb[2 * NPTS];
    float wBest = INFINITY;           // cached wave max (valid across skips)

    for (int t = 0; t < S; ++t) {
        if (tid == 0) s_idx[t] = last;          // LDS only - no global store
        const int buf = t & 1;

        // ---- wave-level prune test (uniform operands)
        const float gx = fmaxf(fmaxf(bxl - px, px - bxh), 0.0f);
        const float gy = fmaxf(fmaxf(byl - py, py - byh), 0.0f);
        const float gz = fmaxf(fmaxf(bzl - pz, pz - bzh), 0.0f);
        const float lb = gx * gx + gy * gy + gz * gz;

        if (!(lb * PRUNE_C >= wBest)) {
            // ---- value-only update (r18-verbatim, 8 VALU/pt)
            float bestv = -INFINITY;
#pragma unroll
            for (int k = 0; k < PPT; ++k) {
                const float dx = X[k] - px, dy = Y[k] - py, dz = Z[k] - pz;
                const float d  = __builtin_fmaf(dz, dz, __builtin_fmaf(dx, dx, dy * dy));
                const float md = fminf(D[k], d);
                D[k] = md;
                bestv = fmaxf(bestv, md);
            }
            const unsigned mybits = __float_as_uint(bestv);

            // ---- wave max via DPP (r13-proven ctrl sequence)
            unsigned red = mybits;
#define DPP_MAX_STEP(CTRL)                                                     \
            {                                                                  \
                const unsigned tpp = (unsigned)__builtin_amdgcn_update_dpp(    \
                    0, (int)red, (CTRL), 0xf, 0xf, true);                      \
                red = (tpp > red) ? tpp : red;                                 \
            }
            DPP_MAX_STEP(0x111)   // row_shr:1
            DPP_MAX_STEP(0x112)   // row_shr:2
            DPP_MAX_STEP(0x114)   // row_shr:4
            DPP_MAX_STEP(0x118)   // row_shr:8
            DPP_MAX_STEP(0x142)   // row_bcast:15
            DPP_MAX_STEP(0x143)   // row_bcast:31
#undef DPP_MAX_STEP
            const unsigned bu = (unsigned)__builtin_amdgcn_readlane((int)red, 63);
            wBest = __uint_as_float(bu);

            // ---- candidate resolve (rare path) + coords of lowest-k-at-max
            unsigned mo = 0xFFFFFFFFu;
            float cx = 0.f, cy = 0.f, cz = 0.f;
            const bool cand = (mybits == bu);
            if (cand) {
#pragma unroll
                for (int k = PPT - 1; k >= 0; --k) {       // ends at LOWEST k
                    if (__float_as_uint(D[k]) == mybits) {
                        mo = (VI[k >> 1] >> ((k & 1) * 16)) & 0xFFFFu;
                        cx = X[k]; cy = Y[k]; cz = Z[k];
                    }
                }
            }
            const unsigned long long m = __ballot(cand);
            bool owner = cand;
            if (__popcll(m) > 1) {               // wave-uniform, exact-tie-only
                unsigned mn = mo;
#pragma unroll
                for (int off = 32; off >= 1; off >>= 1) {
                    const unsigned o = __shfl_xor(mn, off);
                    mn = (o < mn) ? o : mn;
                }
                owner = cand && (mo == mn);      // unique: orig indices distinct
            }
            if (owner) {
                s_wpk[buf][wid] = ((unsigned long long)bu << 32)
                                | (unsigned long long)(0xFFFFFFFFu - mo);
                s_cx[buf][wid] = cx;
                s_cy[buf][wid] = cy;
                s_cz[buf][wid] = cz;
            }
        } else {
            // skipped: D unchanged -> slot content still valid; copy parity
            if (lane == 0) {
                s_wpk[buf][wid] = s_wpk[buf ^ 1][wid];
                s_cx[buf][wid] = s_cx[buf ^ 1][wid];
                s_cy[buf][wid] = s_cy[buf ^ 1][wid];
                s_cz[buf][wid] = s_cz[buf ^ 1][wid];
            }
        }
        __syncthreads();                         // the ONE barrier

        // ---- all threads: 16-slot broadcast scan; coords from winner slot
        unsigned long long win = s_wpk[buf][0];
        int w = 0;
#pragma unroll
        for (int w2 = 1; w2 < NWAVE; ++w2) {
            const unsigned long long pw = s_wpk[buf][w2];
            if (pw > win) { win = pw; w = w2; }
        }
        last = (int)(0xFFFFFFFFu - (unsigned)(win & 0xFFFFFFFFull));
        px = s_cx[buf][w];
        py = s_cy[buf][w];
        pz = s_cz[buf][w];
    }

    __syncthreads();
    if (!FUSED) {
        for (int i = tid; i < S; i += NTH) idx_out[b * S + i] = s_idx[i];
    } else {
        for (int i = tid; i < CFEAT * S; i += NTH) {
            const int c = i / S, s = i - c * S;
            const long r = (long)b * CFEAT + c;
            out[r * S + s] = x[r * NPTS + s_idx[s]];
        }
        const long base2 = (long)BATCH * CFEAT * S;
        for (int i = tid; i < 3 * S; i += NTH) {
            const int c = i / S, s = i - c * S;
            const long r = (long)b * 3 + c;
            out[base2 + r * S + s] = xyz[r * NPTS + s_idx[s]];
        }
    }
}

// ---------------------------------------------------------------------------
// Gather kernel (full-chip): out = concat( x_s [B][C][S], xyz_s [B][3][S] ).
// ---------------------------------------------------------------------------
__global__ void gather_kernel(const float* __restrict__ x,
                              const float* __restrict__ xyz,
                              const int* __restrict__ idx,
                              float* __restrict__ out,
                              int S) {
    const long nxs   = (long)BATCH * CFEAT * S;
    const long total = nxs + (long)BATCH * 3 * S;
    for (long i = (long)blockIdx.x * blockDim.x + threadIdx.x; i < total;
         i += (long)gridDim.x * blockDim.x) {
        if (i < nxs) {
            const int s  = (int)(i % S);
            const long r = i / S;            // b*C + c
            const int b  = (int)(r / CFEAT);
            const int p  = idx[b * S + s];
            out[i] = x[r * NPTS + p];
        } else {
            const long j = i - nxs;
            const int s  = (int)(j % S);
            const long r = j / S;            // b*3 + c
            const int b  = (int)(r / 3);
            const int p  = idx[b * S + s];
            out[i] = xyz[r * NPTS + p];
        }
    }
}

extern "C" void kernel_launch(void* const* d_in, const int* in_sizes, int n_in,
                              void* d_out, int out_size, void* d_ws, size_t ws_size,
                              hipStream_t stream) {
    const float* x   = nullptr;   // [B, C, N]
    const float* xyz = nullptr;   // [B, 3, N]
    for (int i = 0; i < n_in; ++i) {
        if (in_sizes[i] == BATCH * CFEAT * NPTS)  x   = (const float*)d_in[i];
        else if (in_sizes[i] == BATCH * 3 * NPTS) xyz = (const float*)d_in[i];
    }
    float* out = (float*)d_out;
    const int S = out_size / (BATCH * (CFEAT + 3));

    const size_t need = (size_t)BATCH * (size_t)S * sizeof(int);
    if (ws_size >= need && d_ws != nullptr) {
        int* idx = (int*)d_ws;
        fps_kernel<false><<<BATCH, NTH, 0, stream>>>(xyz, nullptr, idx, nullptr, S);
        gather_kernel<<<2048, 256, 0, stream>>>(x, xyz, idx, out, S);
    } else {
        fps_kernel<true><<<BATCH, NTH, 0, stream>>>(xyz, x, nullptr, out, S);
    }
}

// Round 20
// 4540.278 us; speedup vs baseline: 1.5894x; 1.5894x over previous
//
#include <hip/hip_runtime.h>
#include <hip/hip_bf16.h>

#pragma clang fp contract(off)

#define NTH   1024      // 16 waves, 1 block per CU
#define PPT   16        // NTH*PPT == NPTS
#define NPTS  16384
#define BATCH 16
#define CFEAT 128
#define SMAX  4096
#define NWAVE (NTH / 64)
// Prune margin (r15-proven exact): skip iff lb*PRUNE_C >= waveMaxD.
#define PRUNE_C 0.999995f

__device__ __forceinline__ unsigned spread3(unsigned v) {
    v &= 0x3FFu;
    v = (v | (v << 16)) & 0x030000FFu;
    v = (v | (v << 8))  & 0x0300F00Fu;
    v = (v | (v << 4))  & 0x030C30C3u;
    v = (v | (v << 2))  & 0x09249249u;
    return v;
}
__device__ __forceinline__ unsigned qz10(float v) {
    int q = (int)((v + 6.0f) * (1023.0f / 12.0f));   // layout-only
    q = q < 0 ? 0 : (q > 1023 ? 1023 : q);
    return (unsigned)q;
}
__device__ __forceinline__ unsigned morton30(float x, float y, float z) {
    return (spread3(qz10(x)) << 2) | (spread3(qz10(y)) << 1) | spread3(qz10(z));
}

// ---------------------------------------------------------------------------
// FPS kernel, one block per batch.
// CORRECTNESS INVARIANTS (proven r0-r19; do not change):
//   * d  = fma(dz,dz, fma(dx,dx, dy*dy))   [XLA contraction form]
//   * md = fminf(D[k], d)
//   * argmax: max value, ties -> LOWEST ORIGINAL point index
//   * emission: idx[t] = last BEFORE the update pass
// HARD RULE (r17+r19 regressions, both ~2x): X/Y/Z/D arrays may ONLY be
// accessed by the simple unrolled update loop. Any select-chained or
// runtime-patterned read of them wrecks AGPR allocation.
// r20 machinery (r18 + two nibbles):
//   * online bgg tracking in the update loop (+3 ops/pt, compile-time VI
//     extracts only) replaces the 16-step candidate rescan (~180cyc on every
//     active wave). Strict > keeps lowest-k-at-max == r18's rescan result.
//   * readfirstlane(last) -> compiler can emit scalar (SMEM) coord loads.
//   * rest r18-verbatim: counting sort, wave bbox prune, DPP wave max,
//     atomicMax u64 rotating cell, LDS idx ring dumped post-loop.
// ---------------------------------------------------------------------------
template <bool FUSED>
__global__ __launch_bounds__(NTH) void fps_kernel(const float* __restrict__ xyz,
                                                  const float* __restrict__ x,
                                                  int* __restrict__ idx_out,
                                                  float* __restrict__ out,
                                                  int S) {
    const int b    = blockIdx.x;
    const int tid  = threadIdx.x;
    const int wid  = tid >> 6;
    const int lane = tid & 63;
    const float* __restrict__ xb = xyz + (size_t)b * 3 * NPTS;

    __shared__ unsigned s_ord[NPTS];            // 64 KB: sorted pos -> orig idx
    __shared__ unsigned s_hist[256];
    __shared__ unsigned long long s_slot[4];
    __shared__ int s_idx[SMAX];                 // idx ring (always LDS)

    // ---- phase 0a: bucket histogram
    for (int i = tid; i < 256; i += NTH) s_hist[i] = 0;
    __syncthreads();
    for (int k = 0; k < PPT; ++k) {
        const int p = k * NTH + tid;
        const unsigned m = morton30(xb[p], xb[NPTS + p], xb[2 * NPTS + p]);
        atomicAdd(&s_hist[m >> 22], 1u);
    }
    __syncthreads();
    // ---- phase 0b: exclusive prefix (serial, one-time)
    if (tid == 0) {
        unsigned acc = 0;
        for (int i = 0; i < 256; ++i) { const unsigned c = s_hist[i]; s_hist[i] = acc; acc += c; }
    }
    __syncthreads();
    // ---- phase 0c: scatter orig indices to sorted order
    for (int k = 0; k < PPT; ++k) {
        const int p = k * NTH + tid;
        const unsigned m = morton30(xb[p], xb[NPTS + p], xb[2 * NPTS + p]);
        const unsigned pos = atomicAdd(&s_hist[m >> 22], 1u);
        s_ord[pos] = (unsigned)p;
    }
    if (tid == 0) { s_slot[0] = s_slot[1] = s_slot[2] = s_slot[3] = 0ull; }
    __syncthreads();

    // ---- phase 0d: wave-chunk gather + wave bbox (r17-proven layout)
    float X[PPT], Y[PPT], Z[PPT], D[PPT];
    unsigned VI[PPT / 2];
    float bxl =  INFINITY, byl =  INFINITY, bzl =  INFINITY;
    float bxh = -INFINITY, byh = -INFINITY, bzh = -INFINITY;
#pragma unroll
    for (int k = 0; k < PPT; ++k) {
        const unsigned gi = s_ord[wid * (64 * PPT) + k * 64 + lane];
        const float xx = xb[gi], yy = xb[NPTS + gi], zz = xb[2 * NPTS + gi];
        X[k] = xx; Y[k] = yy; Z[k] = zz; D[k] = INFINITY;
        if ((k & 1) == 0) VI[k >> 1] = gi;
        else              VI[k >> 1] |= (gi << 16);
        bxl = fminf(bxl, xx); bxh = fmaxf(bxh, xx);
        byl = fminf(byl, yy); byh = fmaxf(byh, yy);
        bzl = fminf(bzl, zz); bzh = fmaxf(bzh, zz);
    }
#pragma unroll
    for (int off = 32; off >= 1; off >>= 1) {
        bxl = fminf(bxl, __shfl_xor(bxl, off)); bxh = fmaxf(bxh, __shfl_xor(bxh, off));
        byl = fminf(byl, __shfl_xor(byl, off)); byh = fmaxf(byh, __shfl_xor(byh, off));
        bzl = fminf(bzl, __shfl_xor(bzl, off)); bzh = fmaxf(bzh, __shfl_xor(bzh, off));
    }

    int   last  = 0;
    float px = xb[0], py = xb[NPTS], pz = xb[2 * NPTS];
    float wBest = INFINITY;           // cached wave max (valid across skips)
    unsigned long long myPack = 0;    // cached candidate pack (per lane)

    for (int t = 0; t < S; ++t) {
        if (tid == 0) s_idx[t] = last;          // LDS only - no global store

        // ---- wave-level prune test (uniform operands)
        const float gx = fmaxf(fmaxf(bxl - px, px - bxh), 0.0f);
        const float gy = fmaxf(fmaxf(byl - py, py - byh), 0.0f);
        const float gz = fmaxf(fmaxf(bzl - pz, pz - bzh), 0.0f);
        const float lb = gx * gx + gy * gy + gz * gz;

        if (!(lb * PRUNE_C >= wBest)) {
            // ---- update + online (bestv,bgg) tracking; 11 VALU/pt, no rescan
            float    bestv = -INFINITY;
            unsigned bgg   = 0xFFFFu;
#pragma unroll
            for (int k = 0; k < PPT; ++k) {
                const float dx = X[k] - px, dy = Y[k] - py, dz = Z[k] - pz;
                const float d  = __builtin_fmaf(dz, dz, __builtin_fmaf(dx, dx, dy * dy));
                const float md = fminf(D[k], d);
                D[k] = md;
                const unsigned gg = (k & 1) ? (VI[k >> 1] >> 16)
                                            : (VI[k >> 1] & 0xFFFFu);
                if (md > bestv) { bestv = md; bgg = gg; }   // lowest k at max
            }
            const unsigned mybits = __float_as_uint(bestv);

            // ---- wave max via DPP (r13-proven ctrl sequence)
            unsigned red = mybits;
#define DPP_MAX_STEP(CTRL)                                                     \
            {                                                                  \
                const unsigned tpp = (unsigned)__builtin_amdgcn_update_dpp(    \
                    0, (int)red, (CTRL), 0xf, 0xf, true);                      \
                red = (tpp > red) ? tpp : red;                                 \
            }
            DPP_MAX_STEP(0x111)   // row_shr:1
            DPP_MAX_STEP(0x112)   // row_shr:2
            DPP_MAX_STEP(0x114)   // row_shr:4
            DPP_MAX_STEP(0x118)   // row_shr:8
            DPP_MAX_STEP(0x142)   // row_bcast:15
            DPP_MAX_STEP(0x143)   // row_bcast:31
#undef DPP_MAX_STEP
            const unsigned bu = (unsigned)__builtin_amdgcn_readlane((int)red, 63);
            wBest = __uint_as_float(bu);

            myPack = 0;
            if (mybits == bu) {               // candidate lane(s), ~1 per wave
                myPack = ((unsigned long long)mybits << 32)
                       | (unsigned long long)(0xFFFFFFFFu - bgg);
            }
        }
        // candidates (fresh or cached from skipped iterations) publish
        if (myPack) atomicMax(&s_slot[t & 3], myPack);
        if (tid == 0) s_slot[(t + 2) & 3] = 0ull;      // distance-2 rotate-init
        __syncthreads();                                // the ONE barrier

        const unsigned long long win = s_slot[t & 3];
        last = __builtin_amdgcn_readfirstlane(
                   (int)(0xFFFFFFFFu - (unsigned)(win & 0xFFFFFFFFull)));
        px = xb[last]; py = xb[NPTS + last]; pz = xb[2 * NPTS + last];
    }

    __syncthreads();
    if (!FUSED) {
        for (int i = tid; i < S; i += NTH) idx_out[b * S + i] = s_idx[i];
    } else {
        for (int i = tid; i < CFEAT * S; i += NTH) {
            const int c = i / S, s = i - c * S;
            const long r = (long)b * CFEAT + c;
            out[r * S + s] = x[r * NPTS + s_idx[s]];
        }
        const long base2 = (long)BATCH * CFEAT * S;
        for (int i = tid; i < 3 * S; i += NTH) {
            const int c = i / S, s = i - c * S;
            const long r = (long)b * 3 + c;
            out[base2 + r * S + s] = xyz[r * NPTS + s_idx[s]];
        }
    }
}

// ---------------------------------------------------------------------------
// Gather kernel (full-chip): out = concat( x_s [B][C][S], xyz_s [B][3][S] ).
// ---------------------------------------------------------------------------
__global__ void gather_kernel(const float* __restrict__ x,
                              const float* __restrict__ xyz,
                              const int* __restrict__ idx,
                              float* __restrict__ out,
                              int S) {
    const long nxs   = (long)BATCH * CFEAT * S;
    const long total = nxs + (long)BATCH * 3 * S;
    for (long i = (long)blockIdx.x * blockDim.x + threadIdx.x; i < total;
         i += (long)gridDim.x * blockDim.x) {
        if (i < nxs) {
            const int s  = (int)(i % S);
            const long r = i / S;            // b*C + c
            const int b  = (int)(r / CFEAT);
            const int p  = idx[b * S + s];
            out[i] = x[r * NPTS + p];
        } else {
            const long j = i - nxs;
            const int s  = (int)(j % S);
            const long r = j / S;            // b*3 + c
            const int b  = (int)(r / 3);
            const int p  = idx[b * S + s];
            out[i] = xyz[r * NPTS + p];
        }
    }
}

extern "C" void kernel_launch(void* const* d_in, const int* in_sizes, int n_in,
                              void* d_out, int out_size, void* d_ws, size_t ws_size,
                              hipStream_t stream) {
    const float* x   = nullptr;   // [B, C, N]
    const float* xyz = nullptr;   // [B, 3, N]
    for (int i = 0; i < n_in; ++i) {
        if (in_sizes[i] == BATCH * CFEAT * NPTS)  x   = (const float*)d_in[i];
        else if (in_sizes[i] == BATCH * 3 * NPTS) xyz = (const float*)d_in[i];
    }
    float* out = (float*)d_out;
    const int S = out_size / (BATCH * (CFEAT + 3));

    const size_t need = (size_t)BATCH * (size_t)S * sizeof(int);
    if (ws_size >= need && d_ws != nullptr) {
        int* idx = (int*)d_ws;
        fps_kernel<false><<<BATCH, NTH, 0, stream>>>(xyz, nullptr, idx, nullptr, S);
        gather_kernel<<<2048, 256, 0, stream>>>(x, xyz, idx, out, S);
    } else {
        fps_kernel<true><<<BATCH, NTH, 0, stream>>>(xyz, x, nullptr, out, S);
    }
}

// Round 21
// 4135.979 us; speedup vs baseline: 1.7448x; 1.0978x over previous
//
#include <hip/hip_runtime.h>
#include <hip/hip_bf16.h>

#pragma clang fp contract(off)

#define NTH   1024      // 16 waves, 1 block per CU
#define PPT   16        // NTH*PPT == NPTS
#define NPTS  16384
#define BATCH 16
#define CFEAT 128
#define SMAX  4096
#define NWAVE (NTH / 64)
// Prune margin (r15-proven exact): skip iff lb*PRUNE_C >= waveMaxD.
#define PRUNE_C 0.999995f

typedef __attribute__((ext_vector_type(2))) float f32x2;

__device__ __forceinline__ unsigned spread3(unsigned v) {
    v &= 0x3FFu;
    v = (v | (v << 16)) & 0x030000FFu;
    v = (v | (v << 8))  & 0x0300F00Fu;
    v = (v | (v << 4))  & 0x030C30C3u;
    v = (v | (v << 2))  & 0x09249249u;
    return v;
}
__device__ __forceinline__ unsigned qz10(float v) {
    int q = (int)((v + 6.0f) * (1023.0f / 12.0f));   // layout-only
    q = q < 0 ? 0 : (q > 1023 ? 1023 : q);
    return (unsigned)q;
}
__device__ __forceinline__ unsigned morton30(float x, float y, float z) {
    return (spread3(qz10(x)) << 2) | (spread3(qz10(y)) << 1) | spread3(qz10(z));
}

// ---------------------------------------------------------------------------
// FPS kernel, one block per batch.
// CORRECTNESS INVARIANTS (proven r0-r20; do not change):
//   * d  = fma(dz,dz, fma(dx,dx, dy*dy))   [XLA contraction form]
//   * md = fminf(D[k], d)
//   * argmax: max value, ties -> LOWEST ORIGINAL point index
//   * emission: idx[t] = last BEFORE the update pass
// HARD RULE (r17/r19): register state arrays are touched ONLY by the simple
// unrolled update loop (static indices, no select-chained reads).
// r21 machinery (r20 + XY->LDS to kill the AGPR moves):
//   * register demand cut to Z[16]+D[16]+VI[8] ~= the ~56 arch VGPRs the
//     allocator actually grants (r10-r13 evidence) => no AGPR parking of the
//     hot state; X,Y live in LDS (128KB pool ALIASING the counting sort's
//     dead s_ord; barriers separate the lifetimes).
//   * with ~50% wave-skip (r15 pruning), LDS port demand ~8 waves x 16
//     ds_read_b64 x 4clk ~= 512 clk/iter, fully overlapped with VALU
//     (this is why r14's version of this idea lost: it ran all 16 waves).
//   * ds pattern lane*8B + k*512B: conflict-free.
//   * tail r18/r20-verbatim: DPP wave max, pack+atomicMax rotating cell,
//     one barrier, LDS idx ring, uniform L2 coord fetch.
// ---------------------------------------------------------------------------
template <bool FUSED>
__global__ __launch_bounds__(NTH) void fps_kernel(const float* __restrict__ xyz,
                                                  const float* __restrict__ x,
                                                  int* __restrict__ idx_out,
                                                  float* __restrict__ out,
                                                  int S) {
    const int b    = blockIdx.x;
    const int tid  = threadIdx.x;
    const int wid  = tid >> 6;
    const int lane = tid & 63;
    const float* __restrict__ xb = xyz + (size_t)b * 3 * NPTS;

    // 128KB pool: s_ord (64KB) lives here during setup, s_xy (128KB) after.
    __shared__ __align__(16) char s_pool[NPTS * sizeof(f32x2)];
    unsigned* s_ord = (unsigned*)s_pool;
    f32x2*    s_xy  = (f32x2*)s_pool;
    __shared__ unsigned s_hist[256];
    __shared__ unsigned long long s_slot[4];
    __shared__ int s_idx[SMAX];

    // ---- phase 0a: bucket histogram
    for (int i = tid; i < 256; i += NTH) s_hist[i] = 0;
    __syncthreads();
    for (int k = 0; k < PPT; ++k) {
        const int p = k * NTH + tid;
        const unsigned m = morton30(xb[p], xb[NPTS + p], xb[2 * NPTS + p]);
        atomicAdd(&s_hist[m >> 22], 1u);
    }
    __syncthreads();
    // ---- phase 0b: exclusive prefix (serial, one-time)
    if (tid == 0) {
        unsigned acc = 0;
        for (int i = 0; i < 256; ++i) { const unsigned c = s_hist[i]; s_hist[i] = acc; acc += c; }
    }
    __syncthreads();
    // ---- phase 0c: scatter orig indices to sorted order
    for (int k = 0; k < PPT; ++k) {
        const int p = k * NTH + tid;
        const unsigned m = morton30(xb[p], xb[NPTS + p], xb[2 * NPTS + p]);
        const unsigned pos = atomicAdd(&s_hist[m >> 22], 1u);
        s_ord[pos] = (unsigned)p;
    }
    if (tid == 0) { s_slot[0] = s_slot[1] = s_slot[2] = s_slot[3] = 0ull; }
    __syncthreads();

    // ---- phase 0d-1: capture owned orig indices (VI) + Z + D init
    float Z[PPT], D[PPT];
    unsigned VI[PPT / 2];
#pragma unroll
    for (int k = 0; k < PPT; ++k) {
        const unsigned gi = s_ord[wid * (64 * PPT) + k * 64 + lane];
        if ((k & 1) == 0) VI[k >> 1] = gi;
        else              VI[k >> 1] |= (gi << 16);
        Z[k] = xb[2 * NPTS + gi];
        D[k] = INFINITY;
    }
    __syncthreads();   // ALL s_ord reads complete before s_xy overwrites pool

    // ---- phase 0d-2: populate s_xy (re-read coords from global; one-time)
#pragma unroll
    for (int k = 0; k < PPT; ++k) {
        const int p = wid * (64 * PPT) + k * 64 + lane;
        const unsigned gi = (k & 1) ? (VI[k >> 1] >> 16) : (VI[k >> 1] & 0xFFFFu);
        f32x2 v;
        v.x = xb[gi];
        v.y = xb[NPTS + gi];
        s_xy[p] = v;
    }
    __syncthreads();

    // ---- phase 0d-3: wave bbox (xy from LDS broadcast-friendly reads)
    float bxl =  INFINITY, byl =  INFINITY, bzl =  INFINITY;
    float bxh = -INFINITY, byh = -INFINITY, bzh = -INFINITY;
#pragma unroll
    for (int k = 0; k < PPT; ++k) {
        const f32x2 xy = s_xy[wid * (64 * PPT) + k * 64 + lane];
        bxl = fminf(bxl, xy.x); bxh = fmaxf(bxh, xy.x);
        byl = fminf(byl, xy.y); byh = fmaxf(byh, xy.y);
        bzl = fminf(bzl, Z[k]); bzh = fmaxf(bzh, Z[k]);
    }
#pragma unroll
    for (int off = 32; off >= 1; off >>= 1) {
        bxl = fminf(bxl, __shfl_xor(bxl, off)); bxh = fmaxf(bxh, __shfl_xor(bxh, off));
        byl = fminf(byl, __shfl_xor(byl, off)); byh = fmaxf(byh, __shfl_xor(byh, off));
        bzl = fminf(bzl, __shfl_xor(bzl, off)); bzh = fmaxf(bzh, __shfl_xor(bzh, off));
    }

    int   last  = 0;
    float px = xb[0], py = xb[NPTS], pz = xb[2 * NPTS];
    float wBest = INFINITY;           // cached wave max (valid across skips)
    unsigned long long myPack = 0;    // cached candidate pack (per lane)
    const int pbase = wid * (64 * PPT) + lane;

    for (int t = 0; t < S; ++t) {
        if (tid == 0) s_idx[t] = last;          // LDS only - no global store

        // ---- wave-level prune test (uniform operands)
        const float gx = fmaxf(fmaxf(bxl - px, px - bxh), 0.0f);
        const float gy = fmaxf(fmaxf(byl - py, py - byh), 0.0f);
        const float gz = fmaxf(fmaxf(bzl - pz, pz - bzh), 0.0f);
        const float lb = gx * gx + gy * gy + gz * gz;

        if (!(lb * PRUNE_C >= wBest)) {
            // ---- update: xy from LDS, Z/D/VI in arch regs; online (bestv,bgg)
            float    bestv = -INFINITY;
            unsigned bgg   = 0xFFFFu;
#pragma unroll
            for (int k = 0; k < PPT; ++k) {
                const f32x2 xy = s_xy[pbase + k * 64];
                const float dx = xy.x - px, dy = xy.y - py, dz = Z[k] - pz;
                const float d  = __builtin_fmaf(dz, dz, __builtin_fmaf(dx, dx, dy * dy));
                const float md = fminf(D[k], d);
                D[k] = md;
                const unsigned gg = (k & 1) ? (VI[k >> 1] >> 16)
                                            : (VI[k >> 1] & 0xFFFFu);
                if (md > bestv) { bestv = md; bgg = gg; }   // lowest k at max
            }
            const unsigned mybits = __float_as_uint(bestv);

            // ---- wave max via DPP (r13-proven ctrl sequence)
            unsigned red = mybits;
#define DPP_MAX_STEP(CTRL)                                                     \
            {                                                                  \
                const unsigned tpp = (unsigned)__builtin_amdgcn_update_dpp(    \
                    0, (int)red, (CTRL), 0xf, 0xf, true);                      \
                red = (tpp > red) ? tpp : red;                                 \
            }
            DPP_MAX_STEP(0x111)   // row_shr:1
            DPP_MAX_STEP(0x112)   // row_shr:2
            DPP_MAX_STEP(0x114)   // row_shr:4
            DPP_MAX_STEP(0x118)   // row_shr:8
            DPP_MAX_STEP(0x142)   // row_bcast:15
            DPP_MAX_STEP(0x143)   // row_bcast:31
#undef DPP_MAX_STEP
            const unsigned bu = (unsigned)__builtin_amdgcn_readlane((int)red, 63);
            wBest = __uint_as_float(bu);

            myPack = 0;
            if (mybits == bu) {               // candidate lane(s), ~1 per wave
                myPack = ((unsigned long long)mybits << 32)
                       | (unsigned long long)(0xFFFFFFFFu - bgg);
            }
        }
        // candidates (fresh or cached from skipped iterations) publish
        if (myPack) atomicMax(&s_slot[t & 3], myPack);
        if (tid == 0) s_slot[(t + 2) & 3] = 0ull;      // distance-2 rotate-init
        __syncthreads();                                // the ONE barrier

        const unsigned long long win = s_slot[t & 3];
        last = (int)(0xFFFFFFFFu - (unsigned)(win & 0xFFFFFFFFull));
        px = xb[last]; py = xb[NPTS + last]; pz = xb[2 * NPTS + last];
    }

    __syncthreads();
    if (!FUSED) {
        for (int i = tid; i < S; i += NTH) idx_out[b * S + i] = s_idx[i];
    } else {
        for (int i = tid; i < CFEAT * S; i += NTH) {
            const int c = i / S, s = i - c * S;
            const long r = (long)b * CFEAT + c;
            out[r * S + s] = x[r * NPTS + s_idx[s]];
        }
        const long base2 = (long)BATCH * CFEAT * S;
        for (int i = tid; i < 3 * S; i += NTH) {
            const int c = i / S, s = i - c * S;
            const long r = (long)b * 3 + c;
            out[base2 + r * S + s] = xyz[r * NPTS + s_idx[s]];
        }
    }
}

// ---------------------------------------------------------------------------
// Gather kernel (full-chip): out = concat( x_s [B][C][S], xyz_s [B][3][S] ).
// ---------------------------------------------------------------------------
__global__ void gather_kernel(const float* __restrict__ x,
                              const float* __restrict__ xyz,
                              const int* __restrict__ idx,
                              float* __restrict__ out,
                              int S) {
    const long nxs   = (long)BATCH * CFEAT * S;
    const long total = nxs + (long)BATCH * 3 * S;
    for (long i = (long)blockIdx.x * blockDim.x + threadIdx.x; i < total;
         i += (long)gridDim.x * blockDim.x) {
        if (i < nxs) {
            const int s  = (int)(i % S);
            const long r = i / S;            // b*C + c
            const int b  = (int)(r / CFEAT);
            const int p  = idx[b * S + s];
            out[i] = x[r * NPTS + p];
        } else {
            const long j = i - nxs;
            const int s  = (int)(j % S);
            const long r = j / S;            // b*3 + c
            const int b  = (int)(r / 3);
            const int p  = idx[b * S + s];
            out[i] = xyz[r * NPTS + p];
        }
    }
}

extern "C" void kernel_launch(void* const* d_in, const int* in_sizes, int n_in,
                              void* d_out, int out_size, void* d_ws, size_t ws_size,
                              hipStream_t stream) {
    const float* x   = nullptr;   // [B, C, N]
    const float* xyz = nullptr;   // [B, 3, N]
    for (int i = 0; i < n_in; ++i) {
        if (in_sizes[i] == BATCH * CFEAT * NPTS)  x   = (const float*)d_in[i];
        else if (in_sizes[i] == BATCH * 3 * NPTS) xyz = (const float*)d_in[i];
    }
    float* out = (float*)d_out;
    const int S = out_size / (BATCH * (CFEAT + 3));

    const size_t need = (size_t)BATCH * (size_t)S * sizeof(int);
    if (ws_size >= need && d_ws != nullptr) {
        int* idx = (int*)d_ws;
        fps_kernel<false><<<BATCH, NTH, 0, stream>>>(xyz, nullptr, idx, nullptr, S);
        gather_kernel<<<2048, 256, 0, stream>>>(x, xyz, idx, out, S);
    } else {
        fps_kernel<true><<<BATCH, NTH, 0, stream>>>(xyz, x, nullptr, out, S);
    }
}